// Round 1
// baseline (450.418 us; speedup 1.0000x reference)
//
#include <hip/hip_runtime.h>
#include <hip/hip_bf16.h>
#include <math.h>

typedef __bf16 bf16x4 __attribute__((ext_vector_type(4)));
typedef __bf16 bf16x8 __attribute__((ext_vector_type(8)));
typedef float  f32x4  __attribute__((ext_vector_type(4)));

#define S_LEN 2048
#define BATCH 4
#define DMODEL 1280
#define NHEAD 16
#define DHEAD 80
#define KDIM 1280

__device__ __forceinline__ f32x4 mfma_bf16(bf16x8 a, bf16x8 b, f32x4 c) {
  return __builtin_amdgcn_mfma_f32_16x16x32_bf16(a, b, c, 0, 0, 0);
}

__device__ __forceinline__ void gload16(const void* g, void* l) {
  __builtin_amdgcn_global_load_lds(
      (const __attribute__((address_space(1))) unsigned int*)g,
      (__attribute__((address_space(3))) unsigned int*)l, 16, 0, 0);
}

// ---------------- fp32 -> bf16 cast (vectorized) ----------------
__global__ void cast_f32_to_bf16(const float* __restrict__ in,
                                 __bf16* __restrict__ out, int n4) {
  int i = blockIdx.x * 256 + threadIdx.x;
  if (i >= n4) return;
  float4 v = reinterpret_cast<const float4*>(in)[i];
  bf16x4 o;
  o[0] = (__bf16)v.x; o[1] = (__bf16)v.y; o[2] = (__bf16)v.z; o[3] = (__bf16)v.w;
  reinterpret_cast<bf16x4*>(out)[i] = o;
}

// ---------------- sin/cos tables [S][40] ----------------
__global__ void build_sincos(const float* __restrict__ rot,
                             float* __restrict__ ctab, float* __restrict__ stab, int n) {
  int i = blockIdx.x * 256 + threadIdx.x;
  if (i >= n) return;
  float v = rot[i];
  ctab[i] = cosf(v);
  stab[i] = sinf(v);
}

// ---------------- GEMM: C[N][E] = A[N][1280] * Bw[E][1280]^T + bias ----------------
// MODE 0: scatter bf16 to q[B,H,S,80], k[B,H,S,80], vT[B,H,80,S]
// MODE 1: fp32 out[N][1280]
template <int MODE>
__global__ __launch_bounds__(256) void gemm_bt(
    const __bf16* __restrict__ A, const __bf16* __restrict__ Bw,
    const float* __restrict__ bias, float* __restrict__ outf,
    __bf16* __restrict__ qw, __bf16* __restrict__ kw, __bf16* __restrict__ vtw)
{
  __shared__ __align__(16) char smem[2][2][16384];  // [buf][A/B][128 rows x 128B (BK=64 bf16)]
  const int tid = threadIdx.x;
  const int lane = tid & 63;
  const int w = tid >> 6;
  const int lr = lane & 15, lg = lane >> 4;
  const int rowblk = (w >> 1) * 64, colblk = (w & 1) * 64;
  const int sxz = (lane & 7) << 4;
  const int r0 = blockIdx.x * 128;
  const int c0 = blockIdx.y * 128;
  const char* asrc = (const char*)(A + (size_t)r0 * KDIM);
  const char* bsrc = (const char*)(Bw + (size_t)c0 * KDIM);

  f32x4 acc[4][4] = {};

  auto stage = [&](int buf, int kt) {
    const size_t kb = (size_t)kt * 128;  // byte offset into K dim
#pragma unroll
    for (int i = 0; i < 4; ++i) {
      int L = i * 4096 + tid * 16;
      int r = L >> 7;
      int coff = (L & 127) ^ ((r & 7) << 4);  // inverse-swizzled source
      gload16(asrc + (size_t)r * 2560 + kb + coff, &smem[buf][0][L]);
      gload16(bsrc + (size_t)r * 2560 + kb + coff, &smem[buf][1][L]);
    }
  };

  auto compute = [&](int buf) {
#pragma unroll
    for (int kk = 0; kk < 2; ++kk) {
      const int cb = (kk * 64 + lg * 16) ^ sxz;
      bf16x8 af[4], bfr[4];
#pragma unroll
      for (int rf = 0; rf < 4; ++rf)
        af[rf] = *reinterpret_cast<const bf16x8*>(&smem[buf][0][(rowblk + rf * 16 + lr) * 128 + cb]);
#pragma unroll
      for (int cf = 0; cf < 4; ++cf)
        bfr[cf] = *reinterpret_cast<const bf16x8*>(&smem[buf][1][(colblk + cf * 16 + lr) * 128 + cb]);
#pragma unroll
      for (int rf = 0; rf < 4; ++rf)
#pragma unroll
        for (int cf = 0; cf < 4; ++cf)
          acc[rf][cf] = mfma_bf16(af[rf], bfr[cf], acc[rf][cf]);
    }
  };

  stage(0, 0);
  __syncthreads();
  int cur = 0;
  for (int t = 0; t < 19; ++t) {
    stage(cur ^ 1, t + 1);   // prefetch next K-tile (stays in flight over compute)
    compute(cur);
    __syncthreads();         // drains vmcnt+lgkm
    cur ^= 1;
  }
  compute(cur);

  float biasr[4];
#pragma unroll
  for (int cf = 0; cf < 4; ++cf) biasr[cf] = bias[c0 + colblk + cf * 16 + lr];

  if (MODE == 1) {
#pragma unroll
    for (int rf = 0; rf < 4; ++rf)
#pragma unroll
      for (int cf = 0; cf < 4; ++cf) {
        const int c = c0 + colblk + cf * 16 + lr;
#pragma unroll
        for (int j = 0; j < 4; ++j) {
          const int r = r0 + rowblk + rf * 16 + lg * 4 + j;
          outf[(size_t)r * DMODEL + c] = acc[rf][cf][j] + biasr[cf];
        }
      }
  } else {
    const int which = c0 / DMODEL;  // block-uniform (128 | 1280)
#pragma unroll
    for (int cf = 0; cf < 4; ++cf) {
      const int c = c0 + colblk + cf * 16 + lr;
      const int ee = c - which * DMODEL;
      const int h = ee / DHEAD;
      const int dh = ee - h * DHEAD;
#pragma unroll
      for (int rf = 0; rf < 4; ++rf)
#pragma unroll
        for (int j = 0; j < 4; ++j) {
          const int r = r0 + rowblk + rf * 16 + lg * 4 + j;
          const int s = r >> 2, b = r & 3;
          const __bf16 bv = (__bf16)(acc[rf][cf][j] + biasr[cf]);
          if (which == 0)
            qw[((size_t)(b * NHEAD + h) * S_LEN + s) * DHEAD + dh] = bv;
          else if (which == 1)
            kw[((size_t)(b * NHEAD + h) * S_LEN + s) * DHEAD + dh] = bv;
          else
            vtw[((size_t)(b * NHEAD + h) * DHEAD + dh) * S_LEN + s] = bv;
        }
    }
  }
}

// ---------------- RoPE in-place on q,k; q additionally pre-scaled by scale*log2e ----------------
__global__ void rope_kernel(__bf16* __restrict__ qw, __bf16* __restrict__ kw,
                            const float* __restrict__ ctab, const float* __restrict__ stab,
                            float qscale)
{
  int idx = blockIdx.x * 256 + threadIdx.x;  // 2*64*2048*10 threads
  const int j = idx % 10;
  int rest = idx / 10;
  const int s = rest & (S_LEN - 1);
  rest >>= 11;
  const int bh = rest & 63;
  const int isk = rest >> 6;
  __bf16* base = (isk ? kw : qw) + ((size_t)bh * S_LEN + s) * DHEAD;
  const float4 c4 = *reinterpret_cast<const float4*>(ctab + s * 40 + j * 4);
  const float4 s4 = *reinterpret_cast<const float4*>(stab + s * 40 + j * 4);
  bf16x4 a = *reinterpret_cast<bf16x4*>(base + j * 4);
  bf16x4 b = *reinterpret_cast<bf16x4*>(base + 40 + j * 4);
  const float m = isk ? 1.0f : qscale;
  const float cc[4] = {c4.x, c4.y, c4.z, c4.w};
  const float ss[4] = {s4.x, s4.y, s4.z, s4.w};
#pragma unroll
  for (int t = 0; t < 4; ++t) {
    float fa = (float)a[t], fb = (float)b[t];
    a[t] = (__bf16)((fa * cc[t] - fb * ss[t]) * m);
    b[t] = (__bf16)((fb * cc[t] + fa * ss[t]) * m);
  }
  *reinterpret_cast<bf16x4*>(base + j * 4) = a;
  *reinterpret_cast<bf16x4*>(base + 40 + j * 4) = b;
}

// ---------------- attention: per (bh, 128-row Q tile), full 2048 KV sweep ----------------
__global__ __launch_bounds__(256, 2) void attn_kernel(
    const __bf16* __restrict__ qw, const __bf16* __restrict__ kw,
    const __bf16* __restrict__ vtw, __bf16* __restrict__ ow)
{
  __shared__ __align__(16) char sK[128 * 176];  // [kv 128][80 d + pad], 176B rows -> 2-way max
  __shared__ __align__(16) char sV[80 * 272];   // [dh 80][kv 128 + pad], 272B rows -> 2-way max
  __shared__ __align__(16) char sP[128 * 256];  // [q 128][kv 128] bf16, XOR-swizzled
  __shared__ float sDen[128];

  const int tid = threadIdx.x;
  const int lane = tid & 63;
  const int w = tid >> 6;
  const int lr = lane & 15, lg = lane >> 4;
  const int qt = blockIdx.x, bh = blockIdx.y;

  const char* qbase = (const char*)(qw + ((size_t)bh * S_LEN + qt * 128) * DHEAD);
  const char* kbase = (const char*)(kw + (size_t)bh * S_LEN * DHEAD);
  const char* vbase = (const char*)(vtw + (size_t)bh * DHEAD * S_LEN);

  bf16x8 z8;
#pragma unroll
  for (int i = 0; i < 8; ++i) z8[i] = (__bf16)0.0f;

  // Q fragments held in registers: rows w*32+m*16+lr, k-steps {0..31, 32..63, 64..79+zeropad}
  bf16x8 aq[2][3];
#pragma unroll
  for (int m = 0; m < 2; ++m) {
    const char* rp = qbase + (size_t)(w * 32 + m * 16 + lr) * 160;
    aq[m][0] = *reinterpret_cast<const bf16x8*>(rp + lg * 16);
    aq[m][1] = *reinterpret_cast<const bf16x8*>(rp + 64 + lg * 16);
    aq[m][2] = (lg < 2) ? *reinterpret_cast<const bf16x8*>(rp + 128 + lg * 16) : z8;
  }

  f32x4 accO[5][2] = {};  // O^T[dh=mf*16+lg*4+j][q=w*32+nl*16+lr]
  f32x4 denp[2] = {};     // unreduced row-sum partials

  for (int kt = 0; kt < 16; ++kt) {
    // reg-stage K/V tile (issue global loads early)
    bf16x8 tk[5], tv[5];
#pragma unroll
    for (int i = 0; i < 5; ++i) {
      int c = i * 256 + tid;
      int row = c / 10, slot = c - row * 10;
      tk[i] = *reinterpret_cast<const bf16x8*>(kbase + ((size_t)kt * 128 + row) * 160 + slot * 16);
    }
#pragma unroll
    for (int i = 0; i < 5; ++i) {
      int c = i * 256 + tid;
      int row = c >> 4, slot = c & 15;
      tv[i] = *reinterpret_cast<const bf16x8*>(vbase + (size_t)row * 4096 + (size_t)kt * 256 + slot * 16);
    }
    __syncthreads();  // all waves done reading previous tile
#pragma unroll
    for (int i = 0; i < 5; ++i) {
      int c = i * 256 + tid;
      int row = c / 10, slot = c - row * 10;
      *reinterpret_cast<bf16x8*>(sK + row * 176 + slot * 16) = tk[i];
    }
#pragma unroll
    for (int i = 0; i < 5; ++i) {
      int c = i * 256 + tid;
      int row = c >> 4, slot = c & 15;
      *reinterpret_cast<bf16x8*>(sV + row * 272 + slot * 16) = tv[i];
    }
    __syncthreads();  // staging visible

    // S = Q * K^T  (pre-scaled so p = exp2(S))
    f32x4 sc[2][8] = {};
#pragma unroll
    for (int ks = 0; ks < 3; ++ks) {
      bf16x8 bk[8];
#pragma unroll
      for (int n = 0; n < 8; ++n) {
        if (ks < 2)
          bk[n] = *reinterpret_cast<const bf16x8*>(sK + (n * 16 + lr) * 176 + ks * 64 + lg * 16);
        else
          bk[n] = (lg < 2) ? *reinterpret_cast<const bf16x8*>(sK + (n * 16 + lr) * 176 + 128 + lg * 16) : z8;
      }
#pragma unroll
      for (int m = 0; m < 2; ++m)
#pragma unroll
        for (int n = 0; n < 8; ++n)
          sc[m][n] = mfma_bf16(aq[m][ks], bk[n], sc[m][n]);
    }

    // p = exp2(s), accumulate den partials, write P (wave-private rows, swizzled)
#pragma unroll
    for (int m = 0; m < 2; ++m) {
#pragma unroll
      for (int n = 0; n < 8; ++n) {
        f32x4 p;
#pragma unroll
        for (int j = 0; j < 4; ++j) p[j] = exp2f(sc[m][n][j]);
        denp[m] += p;
#pragma unroll
        for (int j = 0; j < 4; ++j) {
          int row = w * 32 + m * 16 + lg * 4 + j;
          int cb = ((n * 16 + lr) * 2) ^ ((row & 7) << 4);
          *reinterpret_cast<__bf16*>(sP + row * 256 + cb) = (__bf16)p[j];
        }
      }
    }

    // O^T += V^T * P^T
#pragma unroll
    for (int ks = 0; ks < 4; ++ks) {
      bf16x8 av[5], bp[2];
#pragma unroll
      for (int mf = 0; mf < 5; ++mf)
        av[mf] = *reinterpret_cast<const bf16x8*>(sV + (mf * 16 + lr) * 272 + ks * 64 + lg * 16);
#pragma unroll
      for (int nl = 0; nl < 2; ++nl) {
        int row = w * 32 + nl * 16 + lr;
        bp[nl] = *reinterpret_cast<const bf16x8*>(sP + row * 256 + ((ks * 64 + lg * 16) ^ ((row & 7) << 4)));
      }
#pragma unroll
      for (int mf = 0; mf < 5; ++mf)
#pragma unroll
        for (int nl = 0; nl < 2; ++nl)
          accO[mf][nl] = mfma_bf16(av[mf], bp[nl], accO[mf][nl]);
    }
    __syncthreads();  // before next restage
  }

  // reduce den across the 16 lanes that share each row
#pragma unroll
  for (int m = 0; m < 2; ++m)
#pragma unroll
    for (int j = 0; j < 4; ++j) {
      float v = denp[m][j];
      v += __shfl_xor(v, 1, 16);
      v += __shfl_xor(v, 2, 16);
      v += __shfl_xor(v, 4, 16);
      v += __shfl_xor(v, 8, 16);
      if (lr == 0) sDen[w * 32 + m * 16 + lg * 4 + j] = v;
    }
  __syncthreads();  // also orders: all PV reads done before sP reuse below
  float rinv[2];
#pragma unroll
  for (int nl = 0; nl < 2; ++nl) rinv[nl] = 1.0f / sDen[w * 32 + nl * 16 + lr];

  // transpose O^T -> O[q][dh] in sP (reused), packed b64 writes
#pragma unroll
  for (int mf = 0; mf < 5; ++mf)
#pragma unroll
    for (int nl = 0; nl < 2; ++nl) {
      bf16x4 o4;
#pragma unroll
      for (int j = 0; j < 4; ++j) o4[j] = (__bf16)(accO[mf][nl][j] * rinv[nl]);
      int q = w * 32 + nl * 16 + lr;
      *reinterpret_cast<bf16x4*>(sP + q * 160 + (mf * 16 + lg * 4) * 2) = o4;
    }
  __syncthreads();

  const int b = bh >> 4, h = bh & 15;
#pragma unroll
  for (int i = 0; i < 5; ++i) {
    int c = i * 256 + tid;
    int row = c / 10, slot = c - row * 10;
    int token = (qt * 128 + row) * 4 + b;
    *reinterpret_cast<bf16x8*>((char*)ow + (size_t)token * 2560 + h * 160 + slot * 16) =
        *reinterpret_cast<const bf16x8*>(sP + row * 160 + slot * 16);
  }
}

// ---------------- launcher ----------------
extern "C" void kernel_launch(void* const* d_in, const int* in_sizes, int n_in,
                              void* d_out, int out_size, void* d_ws, size_t ws_size,
                              hipStream_t stream)
{
  const float* hidden = (const float*)d_in[0];
  const float* rot    = (const float*)d_in[1];
  const float* w1     = (const float*)d_in[2];
  const float* b1     = (const float*)d_in[3];
  const float* w2     = (const float*)d_in[4];
  const float* b2     = (const float*)d_in[5];
  float* out = (float*)d_out;

  char* ws = (char*)d_ws;
  __bf16* Xbf  = (__bf16*)(ws);                 // 8192x1280 bf16      = 20,971,520 B
  __bf16* W1bf = (__bf16*)(ws + 20971520);      // 3840x1280 bf16      =  9,830,400 B
  __bf16* W2bf = (__bf16*)(ws + 30801920);      // 1280x1280 bf16      =  3,276,800 B
  float*  ctab = (float*)(ws + 34078720);       // 2048x40 f32         =    327,680 B
  float*  stab = (float*)(ws + 34406400);       //                     =    327,680 B
  __bf16* qwp  = (__bf16*)(ws + 34734080);      // [B,H,S,80] bf16     = 20,971,520 B
  __bf16* kwp  = (__bf16*)(ws + 55705600);      // [B,H,S,80] bf16     = 20,971,520 B
  __bf16* vtwp = (__bf16*)(ws + 76677120);      // [B,H,80,S] bf16     = 20,971,520 B
  __bf16* owp  = (__bf16*)(ws + 97648640);      // [S*B,1280] bf16     = 20,971,520 B

  cast_f32_to_bf16<<<10240, 256, 0, stream>>>(hidden, Xbf, 2621440);
  cast_f32_to_bf16<<<4800, 256, 0, stream>>>(w1, W1bf, 1228800);
  cast_f32_to_bf16<<<1600, 256, 0, stream>>>(w2, W2bf, 409600);
  build_sincos<<<320, 256, 0, stream>>>(rot, ctab, stab, 81920);

  gemm_bt<0><<<dim3(64, 30), 256, 0, stream>>>(Xbf, W1bf, b1, nullptr, qwp, kwp, vtwp);

  const float qscale = 1.4426950408889634f / sqrtf(80.0f);  // scale * log2(e), folded into Q
  rope_kernel<<<10240, 256, 0, stream>>>(qwp, kwp, ctab, stab, qscale);

  attn_kernel<<<dim3(16, 64), 256, 0, stream>>>(qwp, kwp, vtwp, owp);

  gemm_bt<1><<<dim3(64, 10), 256, 0, stream>>>(owp, W2bf, b2, out, nullptr, nullptr, nullptr);
}

// Round 2
// 340.038 us; speedup vs baseline: 1.3246x; 1.3246x over previous
//
#include <hip/hip_runtime.h>
#include <hip/hip_bf16.h>
#include <math.h>

typedef __bf16 bf16x4 __attribute__((ext_vector_type(4)));
typedef __bf16 bf16x8 __attribute__((ext_vector_type(8)));
typedef float  f32x4  __attribute__((ext_vector_type(4)));

#define S_LEN 2048
#define BATCH 4
#define DMODEL 1280
#define NHEAD 16
#define DHEAD 80
#define KDIM 1280

__device__ __forceinline__ f32x4 mfma_bf16(bf16x8 a, bf16x8 b, f32x4 c) {
  return __builtin_amdgcn_mfma_f32_16x16x32_bf16(a, b, c, 0, 0, 0);
}

__device__ __forceinline__ void gload16(const void* g, void* l) {
  __builtin_amdgcn_global_load_lds(
      (const __attribute__((address_space(1))) unsigned int*)g,
      (__attribute__((address_space(3))) unsigned int*)l, 16, 0, 0);
}

// ---------------- fp32 -> bf16 cast (vectorized) ----------------
__global__ void cast_f32_to_bf16(const float* __restrict__ in,
                                 __bf16* __restrict__ out, int n4) {
  int i = blockIdx.x * 256 + threadIdx.x;
  if (i >= n4) return;
  float4 v = reinterpret_cast<const float4*>(in)[i];
  bf16x4 o;
  o[0] = (__bf16)v.x; o[1] = (__bf16)v.y; o[2] = (__bf16)v.z; o[3] = (__bf16)v.w;
  reinterpret_cast<bf16x4*>(out)[i] = o;
}

// ---------------- sin/cos tables [S][40] ----------------
__global__ void build_sincos(const float* __restrict__ rot,
                             float* __restrict__ ctab, float* __restrict__ stab, int n) {
  int i = blockIdx.x * 256 + threadIdx.x;
  if (i >= n) return;
  float v = rot[i];
  ctab[i] = cosf(v);
  stab[i] = sinf(v);
}

// ---------------- GEMM: C[N][E] = A[N][1280] * Bw[E][1280]^T + bias ----------------
// MODE 0: scatter bf16 to q[B,H,S,80], k[B,H,S,80], vT[B,H,80,S]
// MODE 1: fp32 out[N][1280]
template <int MODE>
__global__ __launch_bounds__(256) void gemm_bt(
    const __bf16* __restrict__ A, const __bf16* __restrict__ Bw,
    const float* __restrict__ bias, float* __restrict__ outf,
    __bf16* __restrict__ qw, __bf16* __restrict__ kw, __bf16* __restrict__ vtw)
{
  __shared__ __align__(16) char smem[2][2][16384];  // [buf][A/B][128 rows x 128B (BK=64 bf16)]
  const int tid = threadIdx.x;
  const int lane = tid & 63;
  const int w = tid >> 6;
  const int lr = lane & 15, lg = lane >> 4;
  const int rowblk = (w >> 1) * 64, colblk = (w & 1) * 64;
  const int sxz = (lane & 7) << 4;
  const int r0 = blockIdx.x * 128;
  const int c0 = blockIdx.y * 128;
  const char* asrc = (const char*)(A + (size_t)r0 * KDIM);
  const char* bsrc = (const char*)(Bw + (size_t)c0 * KDIM);

  f32x4 acc[4][4] = {};

  auto stage = [&](int buf, int kt) {
    const size_t kb = (size_t)kt * 128;  // byte offset into K dim
#pragma unroll
    for (int i = 0; i < 4; ++i) {
      int L = i * 4096 + tid * 16;
      int r = L >> 7;
      int coff = (L & 127) ^ ((r & 7) << 4);  // inverse-swizzled source
      gload16(asrc + (size_t)r * 2560 + kb + coff, &smem[buf][0][L]);
      gload16(bsrc + (size_t)r * 2560 + kb + coff, &smem[buf][1][L]);
    }
  };

  auto compute = [&](int buf) {
#pragma unroll
    for (int kk = 0; kk < 2; ++kk) {
      const int cb = (kk * 64 + lg * 16) ^ sxz;
      bf16x8 af[4], bfr[4];
#pragma unroll
      for (int rf = 0; rf < 4; ++rf)
        af[rf] = *reinterpret_cast<const bf16x8*>(&smem[buf][0][(rowblk + rf * 16 + lr) * 128 + cb]);
#pragma unroll
      for (int cf = 0; cf < 4; ++cf)
        bfr[cf] = *reinterpret_cast<const bf16x8*>(&smem[buf][1][(colblk + cf * 16 + lr) * 128 + cb]);
#pragma unroll
      for (int rf = 0; rf < 4; ++rf)
#pragma unroll
        for (int cf = 0; cf < 4; ++cf)
          acc[rf][cf] = mfma_bf16(af[rf], bfr[cf], acc[rf][cf]);
    }
  };

  stage(0, 0);
  __syncthreads();
  int cur = 0;
  for (int t = 0; t < 19; ++t) {
    stage(cur ^ 1, t + 1);   // prefetch next K-tile (stays in flight over compute)
    compute(cur);
    __syncthreads();         // drains vmcnt+lgkm
    cur ^= 1;
  }
  compute(cur);

  float biasr[4];
#pragma unroll
  for (int cf = 0; cf < 4; ++cf) biasr[cf] = bias[c0 + colblk + cf * 16 + lr];

  if (MODE == 1) {
#pragma unroll
    for (int rf = 0; rf < 4; ++rf)
#pragma unroll
      for (int cf = 0; cf < 4; ++cf) {
        const int c = c0 + colblk + cf * 16 + lr;
#pragma unroll
        for (int j = 0; j < 4; ++j) {
          const int r = r0 + rowblk + rf * 16 + lg * 4 + j;
          outf[(size_t)r * DMODEL + c] = acc[rf][cf][j] + biasr[cf];
        }
      }
  } else {
    const int which = c0 / DMODEL;  // block-uniform (128 | 1280)
#pragma unroll
    for (int cf = 0; cf < 4; ++cf) {
      const int c = c0 + colblk + cf * 16 + lr;
      const int ee = c - which * DMODEL;
      const int h = ee / DHEAD;
      const int dh = ee - h * DHEAD;
#pragma unroll
      for (int rf = 0; rf < 4; ++rf)
#pragma unroll
        for (int j = 0; j < 4; ++j) {
          const int r = r0 + rowblk + rf * 16 + lg * 4 + j;
          const int s = r >> 2, b = r & 3;
          const __bf16 bv = (__bf16)(acc[rf][cf][j] + biasr[cf]);
          if (which == 0)
            qw[((size_t)(b * NHEAD + h) * S_LEN + s) * DHEAD + dh] = bv;
          else if (which == 1)
            kw[((size_t)(b * NHEAD + h) * S_LEN + s) * DHEAD + dh] = bv;
          else
            vtw[((size_t)(b * NHEAD + h) * DHEAD + dh) * S_LEN + s] = bv;
        }
    }
  }
}

// ---------------- RoPE in-place on q,k; q additionally pre-scaled by scale*log2e ----------------
__global__ void rope_kernel(__bf16* __restrict__ qw, __bf16* __restrict__ kw,
                            const float* __restrict__ ctab, const float* __restrict__ stab,
                            float qscale)
{
  int idx = blockIdx.x * 256 + threadIdx.x;  // 2*64*2048*10 threads
  const int j = idx % 10;
  int rest = idx / 10;
  const int s = rest & (S_LEN - 1);
  rest >>= 11;
  const int bh = rest & 63;
  const int isk = rest >> 6;
  __bf16* base = (isk ? kw : qw) + ((size_t)bh * S_LEN + s) * DHEAD;
  const float4 c4 = *reinterpret_cast<const float4*>(ctab + s * 40 + j * 4);
  const float4 s4 = *reinterpret_cast<const float4*>(stab + s * 40 + j * 4);
  bf16x4 a = *reinterpret_cast<bf16x4*>(base + j * 4);
  bf16x4 b = *reinterpret_cast<bf16x4*>(base + 40 + j * 4);
  const float m = isk ? 1.0f : qscale;
  const float cc[4] = {c4.x, c4.y, c4.z, c4.w};
  const float ss[4] = {s4.x, s4.y, s4.z, s4.w};
#pragma unroll
  for (int t = 0; t < 4; ++t) {
    float fa = (float)a[t], fb = (float)b[t];
    a[t] = (__bf16)((fa * cc[t] - fb * ss[t]) * m);
    b[t] = (__bf16)((fb * cc[t] + fa * ss[t]) * m);
  }
  *reinterpret_cast<bf16x4*>(base + j * 4) = a;
  *reinterpret_cast<bf16x4*>(base + 40 + j * 4) = b;
}

// ---------------- attention v2 ----------------
// 512 threads = 8 waves; wave w owns q rows [w*16, w*16+16) of a 128-row Q tile.
// Swapped QK^T: sc = mfma(K, Q) -> lane holds P[kv = n*16+lg*4+j][q = lr].
// PV uses a PERMUTED k-order (k-slot (lg,j') -> kv = blk*16+lg*4+(j'&3)), so the
// P fragment is lane-local (no shuffles, no LDS round-trip); V is staged into LDS
// pre-permuted to match. K/V next tile register-prefetched before compute (T14).
__global__ __launch_bounds__(512, 4) void attn_kernel(
    const __bf16* __restrict__ qw, const __bf16* __restrict__ kw,
    const __bf16* __restrict__ vtw, __bf16* __restrict__ ow)
{
  __shared__ __align__(16) char sK[128 * 176];  // [kv 128][80 d + pad]; 176B rows -> 2-way max
  __shared__ __align__(16) char sV[80 * 272];   // [dh 80][kv 128 permuted + pad]; 2-way max

  const int tid = threadIdx.x;
  const int lane = tid & 63;
  const int w = tid >> 6;
  const int lr = lane & 15, lg = lane >> 4;

  // XCD-aware mapping: all 16 q-tiles of one bh on one XCD (K/V L2-resident once)
  const int wg = blockIdx.x;            // 0..1023, xcd = wg & 7
  const int local = wg >> 3;            // 0..127
  const int bh = (wg & 7) * 8 + (local >> 4);
  const int qt = local & 15;

  const char* qbase = (const char*)(qw + ((size_t)bh * S_LEN + qt * 128) * DHEAD);
  const char* kbase = (const char*)(kw + (size_t)bh * S_LEN * DHEAD);
  const char* vbase = (const char*)(vtw + (size_t)bh * DHEAD * S_LEN);

  bf16x8 z8;
#pragma unroll
  for (int i = 0; i < 8; ++i) z8[i] = (__bf16)0.0f;

  // Q fragments (B-operand): q row = w*16+lr, d-steps {0..31, 32..63, 64..79+pad}
  bf16x8 aq[3];
  {
    const char* rp = qbase + (size_t)(w * 16 + lr) * 160;
    aq[0] = *reinterpret_cast<const bf16x8*>(rp + lg * 16);
    aq[1] = *reinterpret_cast<const bf16x8*>(rp + 64 + lg * 16);
    aq[2] = (lg < 2) ? *reinterpret_cast<const bf16x8*>(rp + 128 + lg * 16) : z8;
  }

  f32x4 accO[5] = {};  // O[q=lr][dh=mf*16+lg*4+j]
  f32x4 denv = {};     // per-lane partial row sums (q=lr)

  bf16x8 tk[3], tv[3];
  auto load_tile = [&](int kt) {
#pragma unroll
    for (int i = 0; i < 3; ++i) {
      int c = i * 512 + tid;
      if (c < 1280) {
        int row = c / 10, slot = c - row * 10;
        tk[i] = *reinterpret_cast<const bf16x8*>(kbase + ((size_t)kt * 128 + row) * 160 + slot * 16);
      }
    }
#pragma unroll
    for (int i = 0; i < 3; ++i) {
      int c = i * 512 + tid;
      if (c < 1280) {
        int row = c >> 4, u = c & 15;
        tv[i] = *reinterpret_cast<const bf16x8*>(vbase + (size_t)row * 4096 + (size_t)kt * 256 + u * 16);
      }
    }
  };
  auto write_tile = [&]() {
#pragma unroll
    for (int i = 0; i < 3; ++i) {
      int c = i * 512 + tid;
      if (c < 1280) {
        int row = c / 10, slot = c - row * 10;
        *reinterpret_cast<bf16x8*>(sK + row * 176 + slot * 16) = tk[i];
      }
    }
#pragma unroll
    for (int i = 0; i < 3; ++i) {
      int c = i * 512 + tid;
      if (c < 1280) {
        int row = c >> 4, u = c & 15;
        bf16x4 lo, hi;
#pragma unroll
        for (int j = 0; j < 4; ++j) { lo[j] = tv[i][j]; hi[j] = tv[i][4 + j]; }
        const int g0 = 2 * u, g1 = 2 * u + 1;
        const int n0 = g0 >> 2, l0 = g0 & 3;
        const int n1 = g1 >> 2, l1 = g1 & 3;
        *reinterpret_cast<bf16x4*>(sV + row * 272 + (n0 >> 1) * 64 + l0 * 16 + (n0 & 1) * 8) = lo;
        *reinterpret_cast<bf16x4*>(sV + row * 272 + (n1 >> 1) * 64 + l1 * 16 + (n1 & 1) * 8) = hi;
      }
    }
  };

  load_tile(0);
  write_tile();

  for (int kt = 0; kt < 16; ++kt) {
    __syncthreads();                 // staging visible
    if (kt < 15) load_tile(kt + 1);  // issue early; latency hides under compute

    // S^T = K * Q^T  (Q pre-scaled by scale*log2e, so p = exp2(s))
    f32x4 sc[8] = {};
#pragma unroll
    for (int n = 0; n < 8; ++n) {
      const char* kr = sK + (n * 16 + lr) * 176;
      bf16x8 b0 = *reinterpret_cast<const bf16x8*>(kr + lg * 16);
      bf16x8 b1 = *reinterpret_cast<const bf16x8*>(kr + 64 + lg * 16);
      bf16x8 b2 = (lg < 2) ? *reinterpret_cast<const bf16x8*>(kr + 128 + lg * 16) : z8;
      sc[n] = mfma_bf16(b0, aq[0], sc[n]);
      sc[n] = mfma_bf16(b1, aq[1], sc[n]);
      sc[n] = mfma_bf16(b2, aq[2], sc[n]);
    }

    // p = exp2(s); den partials; pack P fragments lane-locally (permuted k-order)
    bf16x8 bp[4];
#pragma unroll
    for (int n = 0; n < 8; ++n) {
      f32x4 p;
#pragma unroll
      for (int j = 0; j < 4; ++j) p[j] = exp2f(sc[n][j]);
      denv += p;
#pragma unroll
      for (int j = 0; j < 4; ++j) bp[n >> 1][(n & 1) * 4 + j] = (__bf16)p[j];
    }

    // O += P*V with permuted k-order; V already stored permuted in sV
#pragma unroll
    for (int s = 0; s < 4; ++s) {
#pragma unroll
      for (int mf = 0; mf < 5; ++mf) {
        bf16x8 av = *reinterpret_cast<const bf16x8*>(sV + (mf * 16 + lr) * 272 + s * 64 + lg * 16);
        accO[mf] = mfma_bf16(av, bp[s], accO[mf]);
      }
    }

    __syncthreads();                 // all LDS reads for this tile done
    if (kt < 15) write_tile();
  }

  // den: in-lane 4 + cross-lg butterfly (all lanes end with den for q=lr)
  float den = denv[0] + denv[1] + denv[2] + denv[3];
  den += __shfl_xor(den, 16);
  den += __shfl_xor(den, 32);
  const float rinv = 1.0f / den;

  // O to LDS (reuse sK), then coalesced global write
  char* sOut = sK;
#pragma unroll
  for (int mf = 0; mf < 5; ++mf) {
    bf16x4 o4;
#pragma unroll
    for (int j = 0; j < 4; ++j) o4[j] = (__bf16)(accO[mf][j] * rinv);
    *reinterpret_cast<bf16x4*>(sOut + (size_t)(w * 16 + lr) * 160 + (mf * 16 + lg * 4) * 2) = o4;
  }
  __syncthreads();

  const int b = bh >> 4, h = bh & 15;
#pragma unroll
  for (int i = 0; i < 3; ++i) {
    int c = i * 512 + tid;
    if (c < 1280) {
      int row = c / 10, slot = c - row * 10;
      int token = (qt * 128 + row) * 4 + b;
      *reinterpret_cast<bf16x8*>((char*)ow + (size_t)token * 2560 + h * 160 + slot * 16) =
          *reinterpret_cast<const bf16x8*>(sOut + row * 160 + slot * 16);
    }
  }
}

// ---------------- launcher ----------------
extern "C" void kernel_launch(void* const* d_in, const int* in_sizes, int n_in,
                              void* d_out, int out_size, void* d_ws, size_t ws_size,
                              hipStream_t stream)
{
  const float* hidden = (const float*)d_in[0];
  const float* rot    = (const float*)d_in[1];
  const float* w1     = (const float*)d_in[2];
  const float* b1     = (const float*)d_in[3];
  const float* w2     = (const float*)d_in[4];
  const float* b2     = (const float*)d_in[5];
  float* out = (float*)d_out;

  char* ws = (char*)d_ws;
  __bf16* Xbf  = (__bf16*)(ws);                 // 8192x1280 bf16      = 20,971,520 B
  __bf16* W1bf = (__bf16*)(ws + 20971520);      // 3840x1280 bf16      =  9,830,400 B
  __bf16* W2bf = (__bf16*)(ws + 30801920);      // 1280x1280 bf16      =  3,276,800 B
  float*  ctab = (float*)(ws + 34078720);       // 2048x40 f32         =    327,680 B
  float*  stab = (float*)(ws + 34406400);       //                     =    327,680 B
  __bf16* qwp  = (__bf16*)(ws + 34734080);      // [B,H,S,80] bf16     = 20,971,520 B
  __bf16* kwp  = (__bf16*)(ws + 55705600);      // [B,H,S,80] bf16     = 20,971,520 B
  __bf16* vtwp = (__bf16*)(ws + 76677120);      // [B,H,80,S] bf16     = 20,971,520 B
  __bf16* owp  = (__bf16*)(ws + 97648640);      // [S*B,1280] bf16     = 20,971,520 B

  cast_f32_to_bf16<<<10240, 256, 0, stream>>>(hidden, Xbf, 2621440);
  cast_f32_to_bf16<<<4800, 256, 0, stream>>>(w1, W1bf, 1228800);
  cast_f32_to_bf16<<<1600, 256, 0, stream>>>(w2, W2bf, 409600);
  build_sincos<<<320, 256, 0, stream>>>(rot, ctab, stab, 81920);

  gemm_bt<0><<<dim3(64, 30), 256, 0, stream>>>(Xbf, W1bf, b1, nullptr, qwp, kwp, vtwp);

  const float qscale = 1.4426950408889634f / sqrtf(80.0f);  // scale * log2(e), folded into Q
  rope_kernel<<<10240, 256, 0, stream>>>(qwp, kwp, ctab, stab, qscale);

  attn_kernel<<<1024, 512, 0, stream>>>(qwp, kwp, vtwp, owp);

  gemm_bt<1><<<dim3(64, 10), 256, 0, stream>>>(owp, W2bf, b2, out, nullptr, nullptr, nullptr);
}

// Round 3
// 312.326 us; speedup vs baseline: 1.4421x; 1.0887x over previous
//
#include <hip/hip_runtime.h>
#include <hip/hip_bf16.h>
#include <math.h>

typedef __bf16 bf16x4 __attribute__((ext_vector_type(4)));
typedef __bf16 bf16x8 __attribute__((ext_vector_type(8)));
typedef float  f32x4  __attribute__((ext_vector_type(4)));

#define S_LEN 2048
#define BATCH 4
#define DMODEL 1280
#define NHEAD 16
#define DHEAD 80
#define KDIM 1280

__device__ __forceinline__ f32x4 mfma_bf16(bf16x8 a, bf16x8 b, f32x4 c) {
  return __builtin_amdgcn_mfma_f32_16x16x32_bf16(a, b, c, 0, 0, 0);
}

__device__ __forceinline__ void gload16(const void* g, void* l) {
  __builtin_amdgcn_global_load_lds(
      (const __attribute__((address_space(1))) unsigned int*)g,
      (__attribute__((address_space(3))) unsigned int*)l, 16, 0, 0);
}

// ---------------- fp32 -> bf16 cast (vectorized) ----------------
__global__ void cast_f32_to_bf16(const float* __restrict__ in,
                                 __bf16* __restrict__ out, int n4) {
  int i = blockIdx.x * 256 + threadIdx.x;
  if (i >= n4) return;
  float4 v = reinterpret_cast<const float4*>(in)[i];
  bf16x4 o;
  o[0] = (__bf16)v.x; o[1] = (__bf16)v.y; o[2] = (__bf16)v.z; o[3] = (__bf16)v.w;
  reinterpret_cast<bf16x4*>(out)[i] = o;
}

// ---------------- sin/cos tables [S][40] ----------------
__global__ void build_sincos(const float* __restrict__ rot,
                             float* __restrict__ ctab, float* __restrict__ stab, int n) {
  int i = blockIdx.x * 256 + threadIdx.x;
  if (i >= n) return;
  float v = rot[i];
  ctab[i] = cosf(v);
  stab[i] = sinf(v);
}

// ---------------- zero page ----------------
__global__ void zero_fill(float* __restrict__ p, int n) {
  int i = blockIdx.x * 256 + threadIdx.x;
  if (i < n) p[i] = 0.0f;
}

// ---------------- GEMM: C[N][E] = A[N][1280] * Bw[E][1280]^T + bias ----------------
// MODE 0: scatter bf16 to q[B,H,S,80], k[B,H,S,80], vT[B,H,80,S] (V sigma-permuted per 32-chunk)
// MODE 1: fp32 out[N][1280]
template <int MODE>
__global__ __launch_bounds__(256) void gemm_bt(
    const __bf16* __restrict__ A, const __bf16* __restrict__ Bw,
    const float* __restrict__ bias, float* __restrict__ outf,
    __bf16* __restrict__ qw, __bf16* __restrict__ kw, __bf16* __restrict__ vtw)
{
  __shared__ __align__(16) char smem[2][2][16384];  // [buf][A/B][128 rows x 128B (BK=64 bf16)]
  const int tid = threadIdx.x;
  const int lane = tid & 63;
  const int w = tid >> 6;
  const int lr = lane & 15, lg = lane >> 4;
  const int rowblk = (w >> 1) * 64, colblk = (w & 1) * 64;
  const int sxz = (lane & 7) << 4;
  const int r0 = blockIdx.x * 128;
  const int c0 = blockIdx.y * 128;
  const char* asrc = (const char*)(A + (size_t)r0 * KDIM);
  const char* bsrc = (const char*)(Bw + (size_t)c0 * KDIM);

  f32x4 acc[4][4] = {};

  auto stage = [&](int buf, int kt) {
    const size_t kb = (size_t)kt * 128;  // byte offset into K dim
#pragma unroll
    for (int i = 0; i < 4; ++i) {
      int L = i * 4096 + tid * 16;
      int r = L >> 7;
      int coff = (L & 127) ^ ((r & 7) << 4);  // inverse-swizzled source
      gload16(asrc + (size_t)r * 2560 + kb + coff, &smem[buf][0][L]);
      gload16(bsrc + (size_t)r * 2560 + kb + coff, &smem[buf][1][L]);
    }
  };

  auto compute = [&](int buf) {
#pragma unroll
    for (int kk = 0; kk < 2; ++kk) {
      const int cb = (kk * 64 + lg * 16) ^ sxz;
      bf16x8 af[4], bfr[4];
#pragma unroll
      for (int rf = 0; rf < 4; ++rf)
        af[rf] = *reinterpret_cast<const bf16x8*>(&smem[buf][0][(rowblk + rf * 16 + lr) * 128 + cb]);
#pragma unroll
      for (int cf = 0; cf < 4; ++cf)
        bfr[cf] = *reinterpret_cast<const bf16x8*>(&smem[buf][1][(colblk + cf * 16 + lr) * 128 + cb]);
#pragma unroll
      for (int rf = 0; rf < 4; ++rf)
#pragma unroll
        for (int cf = 0; cf < 4; ++cf)
          acc[rf][cf] = mfma_bf16(af[rf], bfr[cf], acc[rf][cf]);
    }
  };

  stage(0, 0);
  __syncthreads();
  int cur = 0;
  for (int t = 0; t < 19; ++t) {
    stage(cur ^ 1, t + 1);   // prefetch next K-tile (stays in flight over compute)
    compute(cur);
    __syncthreads();         // drains vmcnt+lgkm
    cur ^= 1;
  }
  compute(cur);

  float biasr[4];
#pragma unroll
  for (int cf = 0; cf < 4; ++cf) biasr[cf] = bias[c0 + colblk + cf * 16 + lr];

  if (MODE == 1) {
#pragma unroll
    for (int rf = 0; rf < 4; ++rf)
#pragma unroll
      for (int cf = 0; cf < 4; ++cf) {
        const int c = c0 + colblk + cf * 16 + lr;
#pragma unroll
        for (int j = 0; j < 4; ++j) {
          const int r = r0 + rowblk + rf * 16 + lg * 4 + j;
          outf[(size_t)r * DMODEL + c] = acc[rf][cf][j] + biasr[cf];
        }
      }
  } else {
    const int which = c0 / DMODEL;  // block-uniform (128 | 1280)
#pragma unroll
    for (int cf = 0; cf < 4; ++cf) {
      const int c = c0 + colblk + cf * 16 + lr;
      const int ee = c - which * DMODEL;
      const int h = ee / DHEAD;
      const int dh = ee - h * DHEAD;
#pragma unroll
      for (int rf = 0; rf < 4; ++rf)
#pragma unroll
        for (int j = 0; j < 4; ++j) {
          const int r = r0 + rowblk + rf * 16 + lg * 4 + j;
          const int s = r >> 2, b = r & 3;
          const __bf16 bv = (__bf16)(acc[rf][cf][j] + biasr[cf]);
          if (which == 0)
            qw[((size_t)(b * NHEAD + h) * S_LEN + s) * DHEAD + dh] = bv;
          else if (which == 1)
            kw[((size_t)(b * NHEAD + h) * S_LEN + s) * DHEAD + dh] = bv;
          else {
            // sigma-permute within each 32-chunk so contiguous 16B = PV A-fragment
            const int sp = (s & ~31) | ((s & 12) << 1) | ((s & 16) >> 2) | (s & 3);
            vtw[((size_t)(b * NHEAD + h) * DHEAD + dh) * S_LEN + sp] = bv;
          }
        }
    }
  }
}

// ---------------- RoPE in-place on q,k; q additionally pre-scaled by scale*log2e ----------------
__global__ void rope_kernel(__bf16* __restrict__ qw, __bf16* __restrict__ kw,
                            const float* __restrict__ ctab, const float* __restrict__ stab,
                            float qscale)
{
  int idx = blockIdx.x * 256 + threadIdx.x;  // 2*64*2048*10 threads
  const int j = idx % 10;
  int rest = idx / 10;
  const int s = rest & (S_LEN - 1);
  rest >>= 11;
  const int bh = rest & 63;
  const int isk = rest >> 6;
  __bf16* base = (isk ? kw : qw) + ((size_t)bh * S_LEN + s) * DHEAD;
  const float4 c4 = *reinterpret_cast<const float4*>(ctab + s * 40 + j * 4);
  const float4 s4 = *reinterpret_cast<const float4*>(stab + s * 40 + j * 4);
  bf16x4 a = *reinterpret_cast<bf16x4*>(base + j * 4);
  bf16x4 b = *reinterpret_cast<bf16x4*>(base + 40 + j * 4);
  const float m = isk ? 1.0f : qscale;
  const float cc[4] = {c4.x, c4.y, c4.z, c4.w};
  const float ss[4] = {s4.x, s4.y, s4.z, s4.w};
#pragma unroll
  for (int t = 0; t < 4; ++t) {
    float fa = (float)a[t], fb = (float)b[t];
    a[t] = (__bf16)((fa * cc[t] - fb * ss[t]) * m);
    b[t] = (__bf16)((fb * cc[t] + fa * ss[t]) * m);
  }
  *reinterpret_cast<bf16x4*>(base + j * 4) = a;
  *reinterpret_cast<bf16x4*>(base + 40 + j * 4) = b;
}

// ---------------- attention v3 ----------------
// 256 threads = 4 waves; wave w owns q rows [w*32, w*32+32). kv-tile 64, 32 iters.
// LDS in MFMA-fragment order (slot*1024 + lane*16): conflict-free reads AND
// global_load_lds staging. Swapped QK^T -> lane-local P; PV k-order permuted via
// sigma-permuted V storage (done in gemm epilogue). Double-buffered, counted vmcnt.
__global__ __launch_bounds__(256, 3) void attn_kernel(
    const __bf16* __restrict__ qw, const __bf16* __restrict__ kw,
    const __bf16* __restrict__ vtw, __bf16* __restrict__ ow,
    const float* __restrict__ zp)
{
  __shared__ __align__(1024) char smem[2][24576];  // [buf][K 12KB | V 12KB]

  const int tid = threadIdx.x;
  const int lane = tid & 63;
  const int w = tid >> 6;             // 0..3
  const int lr = lane & 15, lg = lane >> 4;

  // XCD-aware mapping: all 16 q-tiles of one bh on one XCD
  const int wg = blockIdx.x;          // 0..1023
  const int local = wg >> 3;
  const int bh = (wg & 7) * 8 + (local >> 4);
  const int qt = local & 15;

  const char* qbase = (const char*)(qw + ((size_t)bh * S_LEN + qt * 128) * DHEAD);
  const char* kbase = (const char*)(kw + (size_t)bh * S_LEN * DHEAD);
  const char* vbase = (const char*)(vtw + (size_t)bh * DHEAD * S_LEN);
  const char* zpb = (const char*)zp;

  bf16x8 z8;
#pragma unroll
  for (int i = 0; i < 8; ++i) z8[i] = (__bf16)0.0f;

  // Q fragments (B-operand): q = w*32 + m*16 + lr, d-chunks {0..31,32..63,64..79+pad}
  bf16x8 aq[2][3];
#pragma unroll
  for (int m = 0; m < 2; ++m) {
    const char* rp = qbase + (size_t)(w * 32 + m * 16 + lr) * 160;
    aq[m][0] = *reinterpret_cast<const bf16x8*>(rp + lg * 16);
    aq[m][1] = *reinterpret_cast<const bf16x8*>(rp + 64 + lg * 16);
    aq[m][2] = (lg < 2) ? *reinterpret_cast<const bf16x8*>(rp + 128 + lg * 16) : z8;
  }

  // stage one kv-64 tile: 24 slots x 1KB. K slots s=ks*4+n (12), V slots 12+(mf*2+ks2)
  // (mf=5 dummy -> zeropage). Wave w issues slots w*6..w*6+5 (6 gload16/thread).
  auto stage = [&](int buf, int kt) {
#pragma unroll
    for (int i = 0; i < 6; ++i) {
      const int s = w * 6 + i;
      char* dst = &smem[buf][s * 1024];
      const char* src;
      if (s < 12) {
        const int ks = s >> 2, n = s & 3;
        src = (ks == 2 && lg >= 2)
                ? zpb + lane * 16
                : kbase + (size_t)(kt * 64 + n * 16 + lr) * 160 + ks * 64 + lg * 16;
      } else {
        const int v = s - 12;
        const int mf = v >> 1, ks2 = v & 1;
        src = (mf == 5)
                ? zpb + lane * 16
                : vbase + (size_t)(mf * 16 + lr) * 4096 + (size_t)(kt * 64 + ks2 * 32 + lg * 8) * 2;
      }
      gload16(src, dst);
    }
  };

  f32x4 accO[5][2] = {};  // O[dh = mf*16+lg*4+j][q = w*32 + m*16 + lr]
  f32x4 denp[2] = {};

  stage(0, 0);
  asm volatile("s_waitcnt vmcnt(0)" ::: "memory");
  __builtin_amdgcn_s_barrier();
  __builtin_amdgcn_sched_barrier(0);

  for (int t = 0; t < 32; ++t) {
    const int buf = t & 1;
    if (t < 31) {
      stage(buf ^ 1, t + 1);                          // prefetch stays in flight
      asm volatile("s_waitcnt vmcnt(6)" ::: "memory"); // tile t landed; t+1 flying
    } else {
      asm volatile("s_waitcnt vmcnt(0)" ::: "memory");
    }
    __builtin_amdgcn_sched_barrier(0);
    __builtin_amdgcn_s_barrier();   // tile t visible to all waves
    __builtin_amdgcn_sched_barrier(0);

    const char* Kb = smem[buf];
    const char* Vb = smem[buf] + 12288;

    // S^T = K * Q^T  (Q pre-scaled by scale*log2e, so p = exp2(s))
    f32x4 sc[2][4] = {};
#pragma unroll
    for (int n = 0; n < 4; ++n) {
      bf16x8 af0 = *reinterpret_cast<const bf16x8*>(Kb + (0 * 4 + n) * 1024 + lane * 16);
      bf16x8 af1 = *reinterpret_cast<const bf16x8*>(Kb + (1 * 4 + n) * 1024 + lane * 16);
      bf16x8 af2 = *reinterpret_cast<const bf16x8*>(Kb + (2 * 4 + n) * 1024 + lane * 16);
#pragma unroll
      for (int m = 0; m < 2; ++m) {
        sc[m][n] = mfma_bf16(af0, aq[m][0], sc[m][n]);
        sc[m][n] = mfma_bf16(af1, aq[m][1], sc[m][n]);
        sc[m][n] = mfma_bf16(af2, aq[m][2], sc[m][n]);
      }
    }

    // p = exp2(s); den partials; lane-local P pack (permuted k-order)
    bf16x8 bp[2][2];
#pragma unroll
    for (int m = 0; m < 2; ++m)
#pragma unroll
      for (int n = 0; n < 4; ++n) {
        f32x4 p;
#pragma unroll
        for (int j = 0; j < 4; ++j) p[j] = exp2f(sc[m][n][j]);
        denp[m] += p;
#pragma unroll
        for (int j = 0; j < 4; ++j) bp[m][n >> 1][(n & 1) * 4 + j] = (__bf16)p[j];
      }

    // O += P*V (V pre-permuted in global so fragments are contiguous)
#pragma unroll
    for (int ks2 = 0; ks2 < 2; ++ks2)
#pragma unroll
      for (int mf = 0; mf < 5; ++mf) {
        bf16x8 av = *reinterpret_cast<const bf16x8*>(Vb + (mf * 2 + ks2) * 1024 + lane * 16);
        accO[mf][0] = mfma_bf16(av, bp[0][ks2], accO[mf][0]);
        accO[mf][1] = mfma_bf16(av, bp[1][ks2], accO[mf][1]);
      }

    __builtin_amdgcn_sched_barrier(0);
    __builtin_amdgcn_s_barrier();   // reads done -> next iter may overwrite buf^1
    __builtin_amdgcn_sched_barrier(0);
  }

  __syncthreads();

  // den: in-lane 4 + butterfly across lg (q = w*32 + m*16 + lr)
  float rinv[2];
#pragma unroll
  for (int m = 0; m < 2; ++m) {
    float v = denp[m][0] + denp[m][1] + denp[m][2] + denp[m][3];
    v += __shfl_xor(v, 16);
    v += __shfl_xor(v, 32);
    rinv[m] = 1.0f / v;
  }

  // O -> LDS (reuse smem), then coalesced global write
  char* sOut = smem[0];
#pragma unroll
  for (int mf = 0; mf < 5; ++mf)
#pragma unroll
    for (int m = 0; m < 2; ++m) {
      bf16x4 o4;
#pragma unroll
      for (int j = 0; j < 4; ++j) o4[j] = (__bf16)(accO[mf][m][j] * rinv[m]);
      *reinterpret_cast<bf16x4*>(sOut + (size_t)(w * 32 + m * 16 + lr) * 160 + (mf * 16 + lg * 4) * 2) = o4;
    }
  __syncthreads();

  const int b = bh >> 4, h = bh & 15;
#pragma unroll
  for (int i = 0; i < 5; ++i) {
    int c = i * 256 + tid;
    int row = c / 10, slot = c - row * 10;
    int token = (qt * 128 + row) * 4 + b;
    *reinterpret_cast<bf16x8*>((char*)ow + (size_t)token * 2560 + h * 160 + slot * 16) =
        *reinterpret_cast<const bf16x8*>(sOut + row * 160 + slot * 16);
  }
}

// ---------------- launcher ----------------
extern "C" void kernel_launch(void* const* d_in, const int* in_sizes, int n_in,
                              void* d_out, int out_size, void* d_ws, size_t ws_size,
                              hipStream_t stream)
{
  const float* hidden = (const float*)d_in[0];
  const float* rot    = (const float*)d_in[1];
  const float* w1     = (const float*)d_in[2];
  const float* b1     = (const float*)d_in[3];
  const float* w2     = (const float*)d_in[4];
  const float* b2     = (const float*)d_in[5];
  float* out = (float*)d_out;

  char* ws = (char*)d_ws;
  __bf16* Xbf  = (__bf16*)(ws);                 // 8192x1280 bf16      = 20,971,520 B
  __bf16* W1bf = (__bf16*)(ws + 20971520);      // 3840x1280 bf16      =  9,830,400 B
  __bf16* W2bf = (__bf16*)(ws + 30801920);      // 1280x1280 bf16      =  3,276,800 B
  float*  ctab = (float*)(ws + 34078720);       // 2048x40 f32         =    327,680 B
  float*  stab = (float*)(ws + 34406400);       //                     =    327,680 B
  __bf16* qwp  = (__bf16*)(ws + 34734080);      // [B,H,S,80] bf16     = 20,971,520 B
  __bf16* kwp  = (__bf16*)(ws + 55705600);      // [B,H,S,80] bf16     = 20,971,520 B
  __bf16* vtwp = (__bf16*)(ws + 76677120);      // [B,H,80,S] bf16 (sigma-permuted) = 20,971,520 B
  __bf16* owp  = (__bf16*)(ws + 97648640);      // [S*B,1280] bf16     = 20,971,520 B
  float*  zp   = (float*)(ws + 118620160);      // 4KB zero page

  cast_f32_to_bf16<<<10240, 256, 0, stream>>>(hidden, Xbf, 2621440);
  cast_f32_to_bf16<<<4800, 256, 0, stream>>>(w1, W1bf, 1228800);
  cast_f32_to_bf16<<<1600, 256, 0, stream>>>(w2, W2bf, 409600);
  build_sincos<<<320, 256, 0, stream>>>(rot, ctab, stab, 81920);
  zero_fill<<<4, 256, 0, stream>>>(zp, 1024);

  gemm_bt<0><<<dim3(64, 30), 256, 0, stream>>>(Xbf, W1bf, b1, nullptr, qwp, kwp, vtwp);

  const float qscale = 1.4426950408889634f / sqrtf(80.0f);  // scale * log2(e), folded into Q
  rope_kernel<<<10240, 256, 0, stream>>>(qwp, kwp, ctab, stab, qscale);

  attn_kernel<<<1024, 256, 0, stream>>>(qwp, kwp, vtwp, owp, zp);

  gemm_bt<1><<<dim3(64, 10), 256, 0, stream>>>(owp, W2bf, b2, out, nullptr, nullptr, nullptr);
}